// Round 1
// baseline (1739.832 us; speedup 1.0000x reference)
//
#include <hip/hip_runtime.h>
#include <hip/hip_bf16.h>
#include <cstdint>

#define BB 2048
#define SS 128
#define DD 512
#define HHID 2048
#define HRR 512
#define EE 8
#define CC 16
#define LSTEPS 5
#define MAXROWS 2560   // 2048 + 8*64 padding, 64-aligned regions
#define NBLK 40        // MAXROWS/64

// ---------------- init ----------------
__global__ __launch_bounds__(256) void init_k(int* active, int* visits, int* cont, double* total){
  int i = blockIdx.x*256 + threadIdx.x;
  if (i < BB){ active[i]=1; visits[i]=0; cont[i]=-1; }
  if (i == 0) *total = 0.0;
}

__global__ __launch_bounds__(64) void stepbegin_k(int* counts, int* cursor){
  int t = threadIdx.x;
  if (t < EE){ counts[t]=0; cursor[t]=0; }
}

// ---------------- mean pool ----------------
__global__ __launch_bounds__(256) void pool_k(const int* __restrict__ ids,
                                              const float* __restrict__ emb,
                                              float* __restrict__ rep){
  __shared__ int sid[SS];
  int b = blockIdx.x, t = threadIdx.x;
  if (t < SS) sid[t] = ids[b*SS + t];
  __syncthreads();
  double a0 = 0.0, a1 = 0.0;
  for (int s = 0; s < SS; ++s){
    const float* er = emb + (size_t)sid[s]*DD;
    a0 += (double)er[t];
    a1 += (double)er[t+256];
  }
  rep[(size_t)b*DD + t]       = (float)(a0 * (1.0/SS));
  rep[(size_t)b*DD + t + 256] = (float)(a1 * (1.0/SS));
}

// ---------------- generic tiled fp32 GEMM ----------------
// C[BM=64 x BN=128 tile] = act(A[M,K] @ W[K,N] + bias (+extra))
// EXPERT: W/bias/extra indexed by blkexp[blockIdx.y]; GATHER_A: A rows via list
// SCATTER_C: C rows via list (skip -1)
template<bool RELU, bool EXPERT, bool GATHER_A, bool SCATTER_C, bool EXTRA>
__global__ __launch_bounds__(256) void gemm_k(
    const float* __restrict__ A, const float* __restrict__ W,
    const float* __restrict__ bias, const float* __restrict__ extra,
    float* __restrict__ Cm, int N, int K, int ldc,
    const int* __restrict__ list, const int* __restrict__ blkexp)
{
  int e = 0;
  if (EXPERT){ e = blkexp[blockIdx.y]; if (e < 0) return; }
  const float* We = W    + (EXPERT ? (size_t)e*(size_t)K*(size_t)N : 0);
  const float* be = bias + (EXPERT ? (size_t)e*(size_t)N : 0);
  const float* xe = EXTRA ? (extra + (size_t)e*(size_t)N) : nullptr;
  const int m0 = blockIdx.y * 64;
  const int n0 = blockIdx.x * 128;

  __shared__ float As[16][65];
  __shared__ __align__(16) float Bs[16][128];

  const int t  = threadIdx.x;
  const int tx = t & 15, ty = t >> 4;
  const int ar = t >> 2;          // 0..63 tile row for A load
  const int ak = (t & 3) << 2;    // 0,4,8,12 k-offset for A load
  const int bk = t >> 4;          // 0..15 k row for B load
  const int bn = (t & 15) << 3;   // 0..120 col for B load

  const float* Arow;
  bool avalid = true;
  {
    int grow = m0 + ar;
    int gi = GATHER_A ? list[grow] : grow;
    if (GATHER_A && gi < 0){ avalid = false; gi = 0; }
    Arow = A + (size_t)gi * (size_t)K;
  }

  float acc[4][8];
  #pragma unroll
  for (int i=0;i<4;++i)
    #pragma unroll
    for (int j=0;j<8;++j) acc[i][j]=0.f;

  for (int k0 = 0; k0 < K; k0 += 16){
    float4 av = make_float4(0.f,0.f,0.f,0.f);
    if (avalid) av = *(const float4*)(Arow + k0 + ak);
    const float* wp = We + (size_t)(k0+bk)*(size_t)N + (n0 + bn);
    const float4 bv0 = *(const float4*)(wp);
    const float4 bv1 = *(const float4*)(wp+4);
    __syncthreads();
    As[ak+0][ar]=av.x; As[ak+1][ar]=av.y; As[ak+2][ar]=av.z; As[ak+3][ar]=av.w;
    *(float4*)(&Bs[bk][bn])   = bv0;
    *(float4*)(&Bs[bk][bn+4]) = bv1;
    __syncthreads();
    #pragma unroll
    for (int kk=0; kk<16; ++kk){
      const float aa0=As[kk][(ty<<2)+0], aa1=As[kk][(ty<<2)+1];
      const float aa2=As[kk][(ty<<2)+2], aa3=As[kk][(ty<<2)+3];
      const float4 b0=*(const float4*)(&Bs[kk][(tx<<3)]);
      const float4 b1=*(const float4*)(&Bs[kk][(tx<<3)+4]);
      const float aa[4]={aa0,aa1,aa2,aa3};
      const float bb[8]={b0.x,b0.y,b0.z,b0.w,b1.x,b1.y,b1.z,b1.w};
      #pragma unroll
      for (int i=0;i<4;++i)
        #pragma unroll
        for (int j=0;j<8;++j) acc[i][j] = fmaf(aa[i], bb[j], acc[i][j]);
    }
  }

  #pragma unroll
  for (int i=0;i<4;++i){
    int rr = m0 + (ty<<2) + i;
    int orow = rr;
    if (SCATTER_C){ orow = list[rr]; if (orow < 0) continue; }
    float* cp = Cm + (size_t)orow*(size_t)ldc + n0 + (tx<<3);
    float vout[8];
    #pragma unroll
    for (int j=0;j<8;++j){
      float v = acc[i][j] + be[n0+(tx<<3)+j];
      if (EXTRA) v += xe[n0+(tx<<3)+j];
      if (RELU)  v = fmaxf(v, 0.f);
      vout[j]=v;
    }
    *(float4*)cp     = make_float4(vout[0],vout[1],vout[2],vout[3]);
    *(float4*)(cp+4) = make_float4(vout[4],vout[5],vout[6],vout[7]);
  }
}

// ---------------- router decision ----------------
__global__ __launch_bounds__(64) void decide_k(
    const float* __restrict__ hr, const float* __restrict__ rW2, const float* __restrict__ rb2,
    const float* __restrict__ rep, float* __restrict__ final_,
    float* __restrict__ ent, int* __restrict__ wasact,
    int* __restrict__ active, int* __restrict__ visits,
    int* __restrict__ cont, int* __restrict__ counts)
{
  const int b = blockIdx.x;
  const int lane = threadIdx.x;
  __shared__ int sterm;
  if (lane == 0) sterm = 0;
  if (!active[b]){
    if (lane == 0){ ent[b]=0.f; wasact[b]=0; cont[b]=-1; }
    return;
  }
  const float* h = hr + (size_t)b*HRR;
  float p[9];
  #pragma unroll
  for (int j=0;j<9;++j) p[j]=0.f;
  for (int k=lane; k<HRR; k+=64){
    const float hv = h[k];
    const float* wr = rW2 + (size_t)k*9;
    #pragma unroll
    for (int j=0;j<9;++j) p[j] = fmaf(hv, wr[j], p[j]);
  }
  #pragma unroll
  for (int off=32; off>=1; off>>=1){
    #pragma unroll
    for (int j=0;j<9;++j) p[j] += __shfl_xor(p[j], off, 64);
  }
  __syncthreads();
  if (lane == 0){
    const int vis = visits[b];
    float lg[9];
    #pragma unroll
    for (int j=0;j<9;++j) lg[j] = p[j] + rb2[j];
    #pragma unroll
    for (int j=0;j<EE;++j) if ((vis>>j)&1) lg[j] = -1e9f;
    float m = lg[0];
    #pragma unroll
    for (int j=1;j<9;++j) m = fmaxf(m, lg[j]);
    float ex[9]; float s = 0.f;
    #pragma unroll
    for (int j=0;j<9;++j){ ex[j]=expf(lg[j]-m); s+=ex[j]; }
    float ev = 0.f;
    #pragma unroll
    for (int j=0;j<9;++j){ float pr=ex[j]/s; ev -= pr*logf(pr+1e-9f); }
    ent[b]=ev; wasact[b]=1;
    int arg=0; float best=lg[0];
    #pragma unroll
    for (int j=1;j<9;++j) if (lg[j]>best){ best=lg[j]; arg=j; }
    if (arg == EE){
      cont[b]=-1; active[b]=0; sterm=1;
    } else {
      cont[b]=arg; visits[b]=vis|(1<<arg);
      atomicAdd(&counts[arg],1);
    }
  }
  __syncthreads();
  if (sterm){
    const float* rp = rep   + (size_t)b*DD;
    float*       fp = final_+ (size_t)b*DD;
    for (int d=lane; d<DD; d+=64) fp[d]=rp[d];
  }
}

// ---------------- entropy reduce + expert offsets/scan ----------------
__global__ __launch_bounds__(256) void reduce_scan_k(
    const float* __restrict__ ent, const int* __restrict__ wasact,
    const int* __restrict__ counts, int* __restrict__ offs,
    int* __restrict__ blkexp, int* __restrict__ list,
    double* __restrict__ total)
{
  const int t = threadIdx.x;
  double s = 0.0; int c = 0;
  for (int i=t;i<BB;i+=256){ s += (double)ent[i]; c += wasact[i]; }
  __shared__ double sd[256];
  __shared__ int    si[256];
  sd[t]=s; si[t]=c;
  __syncthreads();
  for (int off=128; off>=1; off>>=1){
    if (t < off){ sd[t]+=sd[t+off]; si[t]+=si[t+off]; }
    __syncthreads();
  }
  __shared__ int so[9]; __shared__ int sc[8];
  if (t == 0){
    if (si[0] > 0) *total += sd[0] / (double)si[0];
    int off = 0;
    for (int e2=0;e2<EE;++e2){
      so[e2]=off; sc[e2]=counts[e2]; offs[e2]=off;
      off += (counts[e2] + 63) & ~63;
    }
    so[8]=off; offs[8]=off;
    for (int r=0;r<NBLK;++r){
      int ee=-1;
      for (int e2=0;e2<EE;++e2)
        if (r*64 >= so[e2] && (r+1)*64 <= so[e2+1]) ee=e2;
      blkexp[r]=ee;
    }
  }
  __syncthreads();
  for (int e2=0;e2<EE;++e2){
    for (int s2=so[e2]+sc[e2]+t; s2<so[e2+1]; s2+=256) list[s2]=-1;
  }
}

__global__ __launch_bounds__(256) void scatter_k(const int* __restrict__ cont,
    const int* __restrict__ offs, int* __restrict__ cursor, int* __restrict__ list)
{
  int i = blockIdx.x*256 + threadIdx.x;
  if (i < BB){
    int e = cont[i];
    if (e >= 0){
      int p = atomicAdd(&cursor[e], 1);
      list[offs[e] + p] = i;
    }
  }
}

// ---------------- classifier + entropy output ----------------
__global__ __launch_bounds__(64) void cls_k(const float* __restrict__ rep,
    const float* __restrict__ final_, const int* __restrict__ active,
    const float* __restrict__ cW, const float* __restrict__ cb,
    const double* __restrict__ total, float* __restrict__ out)
{
  const int b = blockIdx.x, lane = threadIdx.x;
  if (b == 0 && lane == 0) out[BB*CC] = (float)(*total);
  const float* src = active[b] ? rep + (size_t)b*DD : final_ + (size_t)b*DD;
  float c[CC];
  #pragma unroll
  for (int j=0;j<CC;++j) c[j]=0.f;
  for (int k=lane;k<DD;k+=64){
    float v = src[k];
    const float* wr = cW + (size_t)k*CC;
    #pragma unroll
    for (int j=0;j<CC;++j) c[j] = fmaf(v, wr[j], c[j]);
  }
  #pragma unroll
  for (int off=32;off>=1;off>>=1){
    #pragma unroll
    for (int j=0;j<CC;++j) c[j] += __shfl_xor(c[j], off, 64);
  }
  if (lane == 0){
    float* op = out + (size_t)b*CC;
    #pragma unroll
    for (int j=0;j<CC;++j) op[j] = c[j] + cb[j];
  }
}

// ---------------- launch ----------------
extern "C" void kernel_launch(void* const* d_in, const int* in_sizes, int n_in,
                              void* d_out, int out_size, void* d_ws, size_t ws_size,
                              hipStream_t stream)
{
  const int*   ids = (const int*)  d_in[0];
  const float* emb = (const float*)d_in[1];
  const float* rW1 = (const float*)d_in[2];
  const float* rb1 = (const float*)d_in[3];
  const float* rW2 = (const float*)d_in[4];
  const float* rb2 = (const float*)d_in[5];
  const float* eW1 = (const float*)d_in[6];
  const float* eb1 = (const float*)d_in[7];
  const float* eW2 = (const float*)d_in[8];
  const float* eb2 = (const float*)d_in[9];
  const float* etag= (const float*)d_in[10];
  const float* cW  = (const float*)d_in[11];
  const float* cb  = (const float*)d_in[12];
  float* out = (float*)d_out;

  float* w      = (float*)d_ws;
  float* rep    = w;
  float* hr     = w + (size_t)BB*DD;
  float* final_ = w + (size_t)2*BB*DD;
  float* hh     = w + (size_t)3*BB*DD;                 // MAXROWS x HHID
  float* ent    = hh + (size_t)MAXROWS*HHID;
  int*   ib     = (int*)(ent + BB);
  int* wasact = ib;  ib += BB;
  int* cont   = ib;  ib += BB;
  int* active = ib;  ib += BB;
  int* visits = ib;  ib += BB;
  int* list   = ib;  ib += MAXROWS;
  int* counts = ib;  ib += 8;
  int* cursor = ib;  ib += 8;
  int* offs   = ib;  ib += 9;
  int* blkexp = ib;  ib += NBLK;
  double* total = (double*)(((uintptr_t)ib + 15) & ~(uintptr_t)15);

  hipMemsetAsync(final_, 0, (size_t)BB*DD*sizeof(float), stream);
  init_k<<<BB/256, 256, 0, stream>>>(active, visits, cont, total);
  pool_k<<<BB, 256, 0, stream>>>(ids, emb, rep);

  for (int step=0; step<LSTEPS; ++step){
    stepbegin_k<<<1, 64, 0, stream>>>(counts, cursor);
    dim3 g1(HRR/128, BB/64);
    gemm_k<true,false,false,false,false><<<g1, 256, 0, stream>>>(
        rep, rW1, rb1, nullptr, hr, HRR, DD, HRR, nullptr, nullptr);
    decide_k<<<BB, 64, 0, stream>>>(hr, rW2, rb2, rep, final_, ent, wasact,
                                    active, visits, cont, counts);
    reduce_scan_k<<<1, 256, 0, stream>>>(ent, wasact, counts, offs, blkexp, list, total);
    scatter_k<<<BB/256, 256, 0, stream>>>(cont, offs, cursor, list);
    dim3 gh(HHID/128, NBLK);
    gemm_k<true,true,true,false,false><<<gh, 256, 0, stream>>>(
        rep, eW1, eb1, nullptr, hh, HHID, DD, HHID, list, blkexp);
    dim3 go(DD/128, NBLK);
    gemm_k<false,true,false,true,true><<<go, 256, 0, stream>>>(
        hh, eW2, eb2, etag, rep, DD, HHID, DD, list, blkexp);
  }

  cls_k<<<BB, 64, 0, stream>>>(rep, final_, active, cW, cb, total, out);
}

// Round 2
// 777.016 us; speedup vs baseline: 2.2391x; 2.2391x over previous
//
#include <hip/hip_runtime.h>
#include <cstdint>

#define BB 2048
#define SS 128
#define DD 512
#define HHID 2048
#define HRR 512
#define EE 8
#define CC 16
#define LSTEPS 5
#define MAXROWS 3072    // 2048 + 8*128, regions 128-aligned
#define NBLK128 24      // MAXROWS/128

typedef __bf16 bf16_t;
typedef __bf16 bf16x8 __attribute__((ext_vector_type(8)));
typedef float  f32x4  __attribute__((ext_vector_type(4)));

#define AS1 __attribute__((address_space(1)))
#define AS3 __attribute__((address_space(3)))

__device__ __forceinline__ void gload16(void* lds, const void* g){
  __builtin_amdgcn_global_load_lds((const AS1 uint32_t*)g, (AS3 uint32_t*)lds, 16, 0, 0);
}

__device__ __forceinline__ void split2(float v, bf16_t* h, bf16_t* l){
  bf16_t hh = (bf16_t)v;
  *h = hh;
  *l = (bf16_t)(v - (float)hh);
}

// ---------------- init ----------------
__global__ __launch_bounds__(256) void init_k(int* active, int* visits, int* cont, double* total){
  int i = blockIdx.x*256 + threadIdx.x;
  if (i < BB){ active[i]=1; visits[i]=0; cont[i]=-1; }
  if (i == 0) *total = 0.0;
}

__global__ __launch_bounds__(64) void stepbegin_k(int* counts, int* cursor){
  int t = threadIdx.x;
  if (t < EE){ counts[t]=0; cursor[t]=0; }
}

// ---------------- weight transpose + bf16 split ----------------
// W [slice][K][N] fp32 -> Wt_hi/lo [slice][N][K] bf16
__global__ __launch_bounds__(256) void tsplit_k(const float* __restrict__ W,
                                                bf16_t* __restrict__ Th,
                                                bf16_t* __restrict__ Tl,
                                                int K, int N){
  const size_t slice = (size_t)blockIdx.z * (size_t)K * (size_t)N;
  const float* Ws = W + slice;
  bf16_t* Ths = Th + slice;
  bf16_t* Tls = Tl + slice;
  __shared__ float tile[64][65];
  const int n0 = blockIdx.x*64, k0 = blockIdx.y*64;
  const int tx = threadIdx.x & 63, ty = threadIdx.x >> 6;
  #pragma unroll
  for (int i=0;i<16;++i){
    int kk = (i<<2) + ty;
    tile[kk][tx] = Ws[(size_t)(k0+kk)*N + n0 + tx];
  }
  __syncthreads();
  #pragma unroll
  for (int i=0;i<16;++i){
    int nn = (i<<2) + ty;
    float v = tile[tx][nn];
    size_t o = (size_t)(n0+nn)*K + k0 + tx;
    bf16_t h = (bf16_t)v;
    Ths[o] = h;
    Tls[o] = (bf16_t)(v - (float)h);
  }
}

// ---------------- mean pool + rep split ----------------
__global__ __launch_bounds__(256) void pool_k(const int* __restrict__ ids,
                                              const float* __restrict__ emb,
                                              float* __restrict__ rep,
                                              bf16_t* __restrict__ rhi,
                                              bf16_t* __restrict__ rlo){
  __shared__ int sid[SS];
  int b = blockIdx.x, t = threadIdx.x;
  if (t < SS) sid[t] = ids[b*SS + t];
  __syncthreads();
  double a0 = 0.0, a1 = 0.0;
  for (int s = 0; s < SS; ++s){
    const float* er = emb + (size_t)sid[s]*DD;
    a0 += (double)er[t];
    a1 += (double)er[t+256];
  }
  float v0 = (float)(a0 * (1.0/SS));
  float v1 = (float)(a1 * (1.0/SS));
  size_t o0 = (size_t)b*DD + t, o1 = o0 + 256;
  rep[o0] = v0; rep[o1] = v1;
  split2(v0, &rhi[o0], &rlo[o0]);
  split2(v1, &rhi[o1], &rlo[o1]);
}

// ---------------- bf16x3 MFMA GEMM ----------------
// C[BM x 128] = act( (Ah+Al)[M,K] @ (Wh+Wl)^T[N,K]^T + bias (+extra) )
// A hi/lo bf16 row-major [*,K]; W hi/lo bf16 TRANSPOSED [N,K].
// EXPERT: weights/bias/extra indexed by blkexp[(m0)>>7]; GATHER: A rows via list
// SCATTER: C rows to rep (+split) via list; SPLITOUT: C -> Ohi/Olo bf16 split.
template<int BM, bool RELU, bool EXPERT, bool GATHER, bool SCATTER, bool EXTRA, bool SPLITOUT>
__global__ __launch_bounds__(256, 2) void mgemm_k(
    const bf16_t* __restrict__ Agh, const bf16_t* __restrict__ Agl,
    const bf16_t* __restrict__ Wgh, const bf16_t* __restrict__ Wgl,
    const float* __restrict__ bias, const float* __restrict__ extra,
    float* __restrict__ Of, bf16_t* __restrict__ Ohi, bf16_t* __restrict__ Olo,
    float* __restrict__ repf, bf16_t* __restrict__ rhi, bf16_t* __restrict__ rlo,
    const bf16_t* __restrict__ zrow,
    const int* __restrict__ list, const int* __restrict__ blkexp,
    int K, int N)
{
  int e = 0;
  if constexpr (EXPERT){ e = blkexp[(blockIdx.y*BM)>>7]; if (e < 0) return; }
  const int m0 = blockIdx.y*BM;
  const int n0 = blockIdx.x*128;
  const bf16_t* Wh = Wgh + (EXPERT ? (size_t)e*(size_t)N*(size_t)K : 0);
  const bf16_t* Wl = Wgl + (EXPERT ? (size_t)e*(size_t)N*(size_t)K : 0);
  const float*  be = bias + (EXPERT ? (size_t)e*N : 0);
  const float*  xe = EXTRA ? (extra + (size_t)e*DD) : nullptr;

  __shared__ __align__(16) bf16_t Ah[BM*64], Al[BM*64];
  __shared__ __align__(16) bf16_t Bh[128*64], Bl[128*64];
  __shared__ int sGi[BM];

  const int t = threadIdx.x;
  const int L = t & 63, w = t >> 6;

  if constexpr (GATHER || SCATTER){
    if (t < BM) sGi[t] = list[m0 + t];
  }

  constexpr int NWN = (BM==128) ? 2 : 4;   // waves along N
  constexpr int WN  = 128/NWN;             // wave N extent
  constexpr int NI  = WN/16;               // N frags per wave
  const int wm = (BM==128) ? (w>>1) : 0;
  const int wn = (BM==128) ? (w&1)  : w;

  f32x4 acc[4][NI];
  #pragma unroll
  for (int i=0;i<4;++i)
    #pragma unroll
    for (int j=0;j<NI;++j){ f32x4 z = {0.f,0.f,0.f,0.f}; acc[i][j]=z; }

  const int rS = L>>3, sS = L&7;
  __syncthreads();

  for (int k0 = 0; k0 < K; k0 += 64){
    // ---- stage: wave0->Ah wave1->Al wave2->Bh wave3->Bl (swizzled source) ----
    if (w < 2){
      const bf16_t* gb = (w==0) ? Agh : Agl;
      bf16_t* sb = (w==0) ? Ah : Al;
      #pragma unroll
      for (int i=0;i<BM/8;++i){
        int r  = i*8 + rS;
        int ss = sS ^ (r & 7);
        const bf16_t* src;
        if constexpr (GATHER){
          int gi = sGi[r];
          src = (gi >= 0) ? (gb + (size_t)gi*K + k0 + ss*8) : (zrow + ss*8);
        } else {
          src = gb + (size_t)(m0+r)*K + k0 + ss*8;
        }
        gload16((char*)sb + i*1024, src);
      }
    } else {
      const bf16_t* gb = (w==2) ? Wh : Wl;
      bf16_t* sb = (w==2) ? Bh : Bl;
      #pragma unroll
      for (int i=0;i<16;++i){
        int r  = i*8 + rS;
        int ss = sS ^ (r & 7);
        const bf16_t* src = gb + (size_t)(n0+r)*K + k0 + ss*8;
        gload16((char*)sb + i*1024, src);
      }
    }
    __syncthreads();   // compiler drains vmcnt before barrier

    #pragma unroll
    for (int kk=0; kk<2; ++kk){
      const int g = (kk<<2) + (L>>4);
      bf16x8 avh[4], avl[4];
      #pragma unroll
      for (int mi=0;mi<4;++mi){
        int row = wm*64 + mi*16 + (L&15);
        int off = row*128 + ((g ^ (row&7))<<4);
        avh[mi] = *(const bf16x8*)((const char*)Ah + off);
        avl[mi] = *(const bf16x8*)((const char*)Al + off);
      }
      bf16x8 bvh[NI], bvl[NI];
      #pragma unroll
      for (int ni=0;ni<NI;++ni){
        int row = wn*WN + ni*16 + (L&15);
        int off = row*128 + ((g ^ (row&7))<<4);
        bvh[ni] = *(const bf16x8*)((const char*)Bh + off);
        bvl[ni] = *(const bf16x8*)((const char*)Bl + off);
      }
      #pragma unroll
      for (int mi=0;mi<4;++mi)
        #pragma unroll
        for (int ni=0;ni<NI;++ni){
          acc[mi][ni] = __builtin_amdgcn_mfma_f32_16x16x32_bf16(avh[mi], bvh[ni], acc[mi][ni], 0,0,0);
          acc[mi][ni] = __builtin_amdgcn_mfma_f32_16x16x32_bf16(avh[mi], bvl[ni], acc[mi][ni], 0,0,0);
          acc[mi][ni] = __builtin_amdgcn_mfma_f32_16x16x32_bf16(avl[mi], bvh[ni], acc[mi][ni], 0,0,0);
        }
    }
    __syncthreads();
  }

  // ---- epilogue: C/D layout col=lane&15, row=(lane>>4)*4+reg ----
  const int cL = L & 15, rL4 = (L>>4)<<2;
  #pragma unroll
  for (int mi=0;mi<4;++mi){
    #pragma unroll
    for (int ni=0;ni<NI;++ni){
      const int col = n0 + wn*WN + ni*16 + cL;
      float bv = be[col];
      if constexpr (EXTRA) bv += xe[col];
      #pragma unroll
      for (int r=0;r<4;++r){
        const int trow = wm*64 + mi*16 + rL4 + r;
        float val = acc[mi][ni][r] + bv;
        if constexpr (RELU) val = fmaxf(val, 0.f);
        if constexpr (SCATTER){
          int orow = sGi[trow];
          if (orow >= 0){
            size_t o = (size_t)orow*DD + col;
            repf[o] = val;
            split2(val, &rhi[o], &rlo[o]);
          }
        } else if constexpr (SPLITOUT){
          size_t o = (size_t)(m0+trow)*(size_t)N + col;
          split2(val, &Ohi[o], &Olo[o]);
        } else {
          Of[(size_t)(m0+trow)*(size_t)N + col] = val;
        }
      }
    }
  }
}

// ---------------- router decision ----------------
__global__ __launch_bounds__(64) void decide_k(
    const float* __restrict__ hr, const float* __restrict__ rW2, const float* __restrict__ rb2,
    const float* __restrict__ rep, float* __restrict__ final_,
    float* __restrict__ ent, int* __restrict__ wasact,
    int* __restrict__ active, int* __restrict__ visits,
    int* __restrict__ cont, int* __restrict__ counts)
{
  const int b = blockIdx.x;
  const int lane = threadIdx.x;
  __shared__ int sterm;
  if (lane == 0) sterm = 0;
  if (!active[b]){
    if (lane == 0){ ent[b]=0.f; wasact[b]=0; cont[b]=-1; }
    return;
  }
  const float* h = hr + (size_t)b*HRR;
  float p[9];
  #pragma unroll
  for (int j=0;j<9;++j) p[j]=0.f;
  for (int k=lane; k<HRR; k+=64){
    const float hv = h[k];
    const float* wr = rW2 + (size_t)k*9;
    #pragma unroll
    for (int j=0;j<9;++j) p[j] = fmaf(hv, wr[j], p[j]);
  }
  #pragma unroll
  for (int off=32; off>=1; off>>=1){
    #pragma unroll
    for (int j=0;j<9;++j) p[j] += __shfl_xor(p[j], off, 64);
  }
  __syncthreads();
  if (lane == 0){
    const int vis = visits[b];
    float lg[9];
    #pragma unroll
    for (int j=0;j<9;++j) lg[j] = p[j] + rb2[j];
    #pragma unroll
    for (int j=0;j<EE;++j) if ((vis>>j)&1) lg[j] = -1e9f;
    float m = lg[0];
    #pragma unroll
    for (int j=1;j<9;++j) m = fmaxf(m, lg[j]);
    float ex[9]; float s = 0.f;
    #pragma unroll
    for (int j=0;j<9;++j){ ex[j]=expf(lg[j]-m); s+=ex[j]; }
    float ev = 0.f;
    #pragma unroll
    for (int j=0;j<9;++j){ float pr=ex[j]/s; ev -= pr*logf(pr+1e-9f); }
    ent[b]=ev; wasact[b]=1;
    int arg=0; float best=lg[0];
    #pragma unroll
    for (int j=1;j<9;++j) if (lg[j]>best){ best=lg[j]; arg=j; }
    if (arg == EE){
      cont[b]=-1; active[b]=0; sterm=1;
    } else {
      cont[b]=arg; visits[b]=vis|(1<<arg);
      atomicAdd(&counts[arg],1);
    }
  }
  __syncthreads();
  if (sterm){
    const float* rp = rep   + (size_t)b*DD;
    float*       fp = final_+ (size_t)b*DD;
    for (int d=lane; d<DD; d+=64) fp[d]=rp[d];
  }
}

// ---------------- entropy reduce + expert offsets (128-aligned) ----------------
__global__ __launch_bounds__(256) void reduce_scan_k(
    const float* __restrict__ ent, const int* __restrict__ wasact,
    const int* __restrict__ counts, int* __restrict__ offs,
    int* __restrict__ blkexp, int* __restrict__ list,
    double* __restrict__ total)
{
  const int t = threadIdx.x;
  double s = 0.0; int c = 0;
  for (int i=t;i<BB;i+=256){ s += (double)ent[i]; c += wasact[i]; }
  __shared__ double sd[256];
  __shared__ int    si[256];
  sd[t]=s; si[t]=c;
  __syncthreads();
  for (int off=128; off>=1; off>>=1){
    if (t < off){ sd[t]+=sd[t+off]; si[t]+=si[t+off]; }
    __syncthreads();
  }
  __shared__ int so[9]; __shared__ int sc[8];
  if (t == 0){
    if (si[0] > 0) *total += sd[0] / (double)si[0];
    int off = 0;
    for (int e2=0;e2<EE;++e2){
      so[e2]=off; sc[e2]=counts[e2]; offs[e2]=off;
      off += (counts[e2] + 127) & ~127;
    }
    so[8]=off; offs[8]=off;
    for (int r=0;r<NBLK128;++r){
      int ee=-1;
      for (int e2=0;e2<EE;++e2)
        if (r*128 >= so[e2] && (r+1)*128 <= so[e2+1]) ee=e2;
      blkexp[r]=ee;
    }
  }
  __syncthreads();
  for (int e2=0;e2<EE;++e2){
    for (int s2=so[e2]+sc[e2]+t; s2<so[e2+1]; s2+=256) list[s2]=-1;
  }
}

__global__ __launch_bounds__(256) void scatter_k(const int* __restrict__ cont,
    const int* __restrict__ offs, int* __restrict__ cursor, int* __restrict__ list)
{
  int i = blockIdx.x*256 + threadIdx.x;
  if (i < BB){
    int e = cont[i];
    if (e >= 0){
      int p = atomicAdd(&cursor[e], 1);
      list[offs[e] + p] = i;
    }
  }
}

// ---------------- classifier + entropy output ----------------
__global__ __launch_bounds__(64) void cls_k(const float* __restrict__ rep,
    const float* __restrict__ final_, const int* __restrict__ active,
    const float* __restrict__ cW, const float* __restrict__ cb,
    const double* __restrict__ total, float* __restrict__ out)
{
  const int b = blockIdx.x, lane = threadIdx.x;
  if (b == 0 && lane == 0) out[BB*CC] = (float)(*total);
  const float* src = active[b] ? rep + (size_t)b*DD : final_ + (size_t)b*DD;
  float c[CC];
  #pragma unroll
  for (int j=0;j<CC;++j) c[j]=0.f;
  for (int k=lane;k<DD;k+=64){
    float v = src[k];
    const float* wr = cW + (size_t)k*CC;
    #pragma unroll
    for (int j=0;j<CC;++j) c[j] = fmaf(v, wr[j], c[j]);
  }
  #pragma unroll
  for (int off=32;off>=1;off>>=1){
    #pragma unroll
    for (int j=0;j<CC;++j) c[j] += __shfl_xor(c[j], off, 64);
  }
  if (lane == 0){
    float* op = out + (size_t)b*CC;
    #pragma unroll
    for (int j=0;j<CC;++j) op[j] = c[j] + cb[j];
  }
}

// ---------------- launch ----------------
extern "C" void kernel_launch(void* const* d_in, const int* in_sizes, int n_in,
                              void* d_out, int out_size, void* d_ws, size_t ws_size,
                              hipStream_t stream)
{
  const int*   ids = (const int*)  d_in[0];
  const float* emb = (const float*)d_in[1];
  const float* rW1 = (const float*)d_in[2];
  const float* rb1 = (const float*)d_in[3];
  const float* rW2 = (const float*)d_in[4];
  const float* rb2 = (const float*)d_in[5];
  const float* eW1 = (const float*)d_in[6];
  const float* eb1 = (const float*)d_in[7];
  const float* eW2 = (const float*)d_in[8];
  const float* eb2 = (const float*)d_in[9];
  const float* etag= (const float*)d_in[10];
  const float* cW  = (const float*)d_in[11];
  const float* cb  = (const float*)d_in[12];
  float* out = (float*)d_out;

  char* p = (char*)d_ws;
  auto alloc = [&](size_t bytes)->char*{
    char* r = p; p += (bytes + 255) & ~(size_t)255; return r;
  };
  float*  rep    = (float*) alloc((size_t)BB*DD*4);
  float*  hr     = (float*) alloc((size_t)BB*HRR*4);
  float*  final_ = (float*) alloc((size_t)BB*DD*4);
  bf16_t* rep_hi = (bf16_t*)alloc((size_t)BB*DD*2);
  bf16_t* rep_lo = (bf16_t*)alloc((size_t)BB*DD*2);
  bf16_t* hh_hi  = (bf16_t*)alloc((size_t)MAXROWS*HHID*2);
  bf16_t* hh_lo  = (bf16_t*)alloc((size_t)MAXROWS*HHID*2);
  bf16_t* rW1t_h = (bf16_t*)alloc((size_t)DD*HRR*2);
  bf16_t* rW1t_l = (bf16_t*)alloc((size_t)DD*HRR*2);
  bf16_t* eW1t_h = (bf16_t*)alloc((size_t)EE*DD*HHID*2);
  bf16_t* eW1t_l = (bf16_t*)alloc((size_t)EE*DD*HHID*2);
  bf16_t* eW2t_h = (bf16_t*)alloc((size_t)EE*DD*HHID*2);
  bf16_t* eW2t_l = (bf16_t*)alloc((size_t)EE*DD*HHID*2);
  bf16_t* zrow   = (bf16_t*)alloc(4096);
  float*  ent    = (float*) alloc((size_t)BB*4);
  int* wasact = (int*)alloc((size_t)BB*4);
  int* cont   = (int*)alloc((size_t)BB*4);
  int* active = (int*)alloc((size_t)BB*4);
  int* visits = (int*)alloc((size_t)BB*4);
  int* list   = (int*)alloc((size_t)MAXROWS*4);
  int* counts = (int*)alloc(64);
  int* cursor = (int*)alloc(64);
  int* offs   = (int*)alloc(64);
  int* blkexp = (int*)alloc(NBLK128*4);
  double* total = (double*)alloc(16);

  hipMemsetAsync(final_, 0, (size_t)BB*DD*4, stream);
  hipMemsetAsync(zrow, 0, 4096, stream);
  init_k<<<BB/256, 256, 0, stream>>>(active, visits, cont, total);

  // weight transpose+split (once per call)
  tsplit_k<<<dim3(HRR/64, DD/64, 1), 256, 0, stream>>>(rW1, rW1t_h, rW1t_l, DD, HRR);
  tsplit_k<<<dim3(HHID/64, DD/64, EE), 256, 0, stream>>>(eW1, eW1t_h, eW1t_l, DD, HHID);
  tsplit_k<<<dim3(DD/64, HHID/64, EE), 256, 0, stream>>>(eW2, eW2t_h, eW2t_l, HHID, DD);

  pool_k<<<BB, 256, 0, stream>>>(ids, emb, rep, rep_hi, rep_lo);

  for (int step=0; step<LSTEPS; ++step){
    stepbegin_k<<<1, 64, 0, stream>>>(counts, cursor);

    // router layer 1: hr = relu(rep @ rW1 + rb1)
    mgemm_k<64, true,false,false,false,false,false><<<dim3(HRR/128, BB/64), 256, 0, stream>>>(
        rep_hi, rep_lo, rW1t_h, rW1t_l, rb1, nullptr,
        hr, nullptr, nullptr, nullptr, nullptr, nullptr,
        zrow, nullptr, nullptr, DD, HRR);

    decide_k<<<BB, 64, 0, stream>>>(hr, rW2, rb2, rep, final_, ent, wasact,
                                    active, visits, cont, counts);
    reduce_scan_k<<<1, 256, 0, stream>>>(ent, wasact, counts, offs, blkexp, list, total);
    scatter_k<<<BB/256, 256, 0, stream>>>(cont, offs, cursor, list);

    // expert layer 1 (gathered rows): hh = relu(rep[list] @ eW1[e] + eb1[e]) -> split bf16
    mgemm_k<128, true,true,true,false,false,true><<<dim3(HHID/128, NBLK128), 256, 0, stream>>>(
        rep_hi, rep_lo, eW1t_h, eW1t_l, eb1, nullptr,
        nullptr, hh_hi, hh_lo, nullptr, nullptr, nullptr,
        zrow, list, blkexp, DD, HHID);

    // expert layer 2: rep[list] = hh @ eW2[e] + eb2[e] + etag[e]  (scatter + re-split)
    mgemm_k<64, false,true,false,true,true,false><<<dim3(DD/128, NBLK128*2), 256, 0, stream>>>(
        hh_hi, hh_lo, eW2t_h, eW2t_l, eb2, etag,
        nullptr, nullptr, nullptr, rep, rep_hi, rep_lo,
        zrow, list, blkexp, HHID, DD);
  }

  cls_k<<<BB, 64, 0, stream>>>(rep, final_, active, cW, cb, total, out);
}